// Round 1
// baseline (66.357 us; speedup 1.0000x reference)
//
#include <hip/hip_runtime.h>

// L1 "order" Chamfer loss, per-coordinate min, mean-reduced to a scalar.
// pred/target: (8192, 128) fp32 = 8192 rows x (64 points x 2 coords).
// out = sum_{n,i,c} 0.5*(min_j|p-t| + min_i|t-p|) * 2^-26.

#define ROWS_PER_BLOCK 16      // 16 waves/block, one wave per row
#define BLOCK_THREADS 1024
#define ROW_FLOATS 128         // 64 points * 2 coords
#define NPTS 64

__global__ __launch_bounds__(BLOCK_THREADS)
void l1_order_loss_kernel(const float* __restrict__ pred,
                          const float* __restrict__ target,
                          float* __restrict__ out) {
    __shared__ float sp[ROWS_PER_BLOCK * ROW_FLOATS];
    __shared__ float st[ROWS_PER_BLOCK * ROW_FLOATS];
    __shared__ float wsum[ROWS_PER_BLOCK];

    const int t = threadIdx.x;
    const long r0 = (long)blockIdx.x * ROWS_PER_BLOCK;

    // Stage 16 rows of each input into LDS: 1024 threads x one float2 each.
    const float2* gp = (const float2*)(pred + r0 * ROW_FLOATS);
    const float2* gt = (const float2*)(target + r0 * ROW_FLOATS);
    ((float2*)sp)[t] = gp[t];
    ((float2*)st)[t] = gt[t];
    __syncthreads();

    const int w    = t >> 6;   // wave id = row within block
    const int lane = t & 63;   // point index within row

    const float2* rp = (const float2*)(sp + w * ROW_FLOATS);
    const float2* rt = (const float2*)(st + w * ROW_FLOATS);

    // Lane owns pred point i=lane (both coords) and target point j=lane.
    const float2 pi = rp[lane];
    const float2 ti = rt[lane];

    float m1x = 1e30f, m1y = 1e30f;  // dist_1: min over target points
    float m2x = 1e30f, m2y = 1e30f;  // dist_2: min over pred points

    // Inner loop: j is wave-uniform -> LDS broadcast reads (no conflicts).
    #pragma unroll
    for (int j = 0; j < NPTS; ++j) {
        const float2 tj = rt[j];
        const float2 pj = rp[j];
        m1x = fminf(m1x, fabsf(pi.x - tj.x));
        m1y = fminf(m1y, fabsf(pi.y - tj.y));
        m2x = fminf(m2x, fabsf(ti.x - pj.x));
        m2y = fminf(m2y, fabsf(ti.y - pj.y));
    }

    float v = (m1x + m1y) + (m2x + m2y);

    // Wave-level shuffle reduction over 64 lanes.
    #pragma unroll
    for (int off = 32; off > 0; off >>= 1)
        v += __shfl_down(v, off);

    if (lane == 0) wsum[w] = v;
    __syncthreads();

    if (t == 0) {
        float s = 0.0f;
        #pragma unroll
        for (int i = 0; i < ROWS_PER_BLOCK; ++i) s += wsum[i];
        // scale = 0.5 / (8192 * 128 * 64) = 2^-27 (exact)
        atomicAdd(out, s * 7.450580596923828e-09f);
    }
}

extern "C" void kernel_launch(void* const* d_in, const int* in_sizes, int n_in,
                              void* d_out, int out_size, void* d_ws, size_t ws_size,
                              hipStream_t stream) {
    const float* pred   = (const float*)d_in[0];
    const float* target = (const float*)d_in[1];
    float* out = (float*)d_out;

    const int n_rows = in_sizes[0] / ROW_FLOATS;       // 8192
    const int grid   = n_rows / ROWS_PER_BLOCK;        // 512

    // d_out is poisoned (0xAA) before every timed launch; zero it first.
    hipMemsetAsync(out, 0, sizeof(float), stream);
    l1_order_loss_kernel<<<grid, BLOCK_THREADS, 0, stream>>>(pred, target, out);
}

// Round 2
// 65.983 us; speedup vs baseline: 1.0057x; 1.0057x over previous
//
#include <hip/hip_runtime.h>

// L1 "order" Chamfer loss, per-coordinate min, mean-reduced to a scalar.
// pred/target: (8192, 128) fp32 = 8192 rows x (64 points x 2 coords).
// out = sum_{n,i,c} 0.5*(min_j|p-t| + min_i|t-p|) * 2^-27-per-element scale.
//
// Structure: one wave per row. Lane i owns pred point i AND target point i
// (divergent float2 loads, coalesced). The j-broadcast stream is wave-uniform,
// so it is read via uniform (scalar) loads -> s_load_dwordx16 batches into
// SGPRs, keeping the inner loop pure VALU (2 instr per coord per direction:
// v_sub_f32 + v_min_f32 with |.| input modifier). No LDS in the hot loop.

#define BLOCK 1024
#define WPB (BLOCK / 64)       // waves (rows) per block = 16
#define ROW_FLOATS 128
#define NPTS 64

__global__ __launch_bounds__(BLOCK)
void l1_order_loss_kernel(const float* __restrict__ pred,
                          const float* __restrict__ target,
                          float* __restrict__ out) {
    __shared__ float wsum[WPB];

    const int t = threadIdx.x;
    const int lane = t & 63;
    const int w = t >> 6;

    // Wave-uniform row index, made explicit for the uniformity analysis.
    int row = blockIdx.x * WPB + w;
    row = __builtin_amdgcn_readfirstlane(row);

    const float* __restrict__ rp = pred   + (size_t)row * ROW_FLOATS;
    const float* __restrict__ rt = target + (size_t)row * ROW_FLOATS;

    // Divergent per-lane points: one coalesced 8B load each.
    const float2 pi = ((const float2*)rp)[lane];
    const float2 ti = ((const float2*)rt)[lane];

    float m1x = 1e30f, m1y = 1e30f;  // dist_1: min over target points j
    float m2x = 1e30f, m2y = 1e30f;  // dist_2: min over pred points j

    // Uniform broadcast stream: scalar loads, fully unrolled so the backend
    // can merge them into s_load_dwordx8/x16 batches.
    #pragma unroll
    for (int j = 0; j < NPTS; ++j) {
        const float tjx = rt[2 * j + 0];
        const float tjy = rt[2 * j + 1];
        const float pjx = rp[2 * j + 0];
        const float pjy = rp[2 * j + 1];
        m1x = fminf(m1x, fabsf(pi.x - tjx));
        m1y = fminf(m1y, fabsf(pi.y - tjy));
        m2x = fminf(m2x, fabsf(ti.x - pjx));
        m2y = fminf(m2y, fabsf(ti.y - pjy));
    }

    float v = (m1x + m1y) + (m2x + m2y);

    // Wave reduction over 64 lanes.
    #pragma unroll
    for (int off = 32; off > 0; off >>= 1)
        v += __shfl_down(v, off);

    if (lane == 0) wsum[w] = v;
    __syncthreads();

    if (t == 0) {
        float s = 0.0f;
        #pragma unroll
        for (int i = 0; i < WPB; ++i) s += wsum[i];
        // scale = 0.5 / (8192 * 128 * 64) = 2^-27 (exact)
        atomicAdd(out, s * 7.450580596923828e-09f);
    }
}

extern "C" void kernel_launch(void* const* d_in, const int* in_sizes, int n_in,
                              void* d_out, int out_size, void* d_ws, size_t ws_size,
                              hipStream_t stream) {
    const float* pred   = (const float*)d_in[0];
    const float* target = (const float*)d_in[1];
    float* out = (float*)d_out;

    const int n_rows = in_sizes[0] / ROW_FLOATS;   // 8192
    const int grid   = n_rows / WPB;               // 512

    // d_out is poisoned (0xAA) before every timed launch; zero it first.
    hipMemsetAsync(out, 0, sizeof(float), stream);
    l1_order_loss_kernel<<<grid, BLOCK, 0, stream>>>(pred, target, out);
}

// Round 3
// 64.578 us; speedup vs baseline: 1.0275x; 1.0218x over previous
//
#include <hip/hip_runtime.h>

// L1 "order" Chamfer loss, per-coordinate min, mean-reduced to a scalar.
// pred/target: (8192, 128) fp32 = 8192 rows x (64 points x 2 coords).
//
// One wave per row. Lane i owns pred point i and target point i (coalesced
// float2 loads). The j-broadcast stream is read as wave-uniform float4 chunks
// (2 points each); subs vectorize to v_pk_add_f32 (packed fp32) and the two
// mins per accumulator fold to v_min3_f32 with |.| modifiers: 8 VALU per
// 2 points vs 16 scalar. Per-block partials go to d_ws via plain stores; a
// second tiny kernel reduces 512 partials and plain-stores d_out (no memset
// node, no same-address atomic tail).

#define BLOCK 1024
#define WPB (BLOCK / 64)       // rows per block = 16
#define ROW_FLOATS 128
#define NCHUNK 32              // 32 float4 chunks = 64 points

typedef float vf4 __attribute__((ext_vector_type(4)));

__global__ __launch_bounds__(BLOCK)
void l1_order_partial_kernel(const float* __restrict__ pred,
                             const float* __restrict__ target,
                             float* __restrict__ partials) {
    __shared__ float wsum[WPB];

    const int t = threadIdx.x;
    const int lane = t & 63;
    const int w = t >> 6;

    int row = __builtin_amdgcn_readfirstlane(blockIdx.x * WPB + w);

    const float* __restrict__ rp = pred   + (size_t)row * ROW_FLOATS;
    const float* __restrict__ rt = target + (size_t)row * ROW_FLOATS;

    // Divergent per-lane points: one coalesced 8B load each.
    const float2 pi = ((const float2*)rp)[lane];
    const float2 ti = ((const float2*)rt)[lane];
    const vf4 piv = {pi.x, pi.y, pi.x, pi.y};
    const vf4 tiv = {ti.x, ti.y, ti.x, ti.y};

    float m1x = 1e30f, m1y = 1e30f;  // dist_1: min over target points j
    float m2x = 1e30f, m2y = 1e30f;  // dist_2: min over pred points j

    const vf4* __restrict__ rt4 = (const vf4*)rt;
    const vf4* __restrict__ rp4 = (const vf4*)rp;

    #pragma unroll
    for (int c = 0; c < NCHUNK; ++c) {
        const vf4 dt = piv - rt4[c];   // 2x v_pk_add_f32 (neg)
        const vf4 dp = tiv - rp4[c];
        // v_min3_f32 with |.| input modifiers: 1 instr per accumulator.
        m1x = fminf(fminf(fabsf(dt.x), fabsf(dt.z)), m1x);
        m1y = fminf(fminf(fabsf(dt.y), fabsf(dt.w)), m1y);
        m2x = fminf(fminf(fabsf(dp.x), fabsf(dp.z)), m2x);
        m2y = fminf(fminf(fabsf(dp.y), fabsf(dp.w)), m2y);
    }

    float v = (m1x + m1y) + (m2x + m2y);

    #pragma unroll
    for (int off = 32; off > 0; off >>= 1)
        v += __shfl_down(v, off);

    if (lane == 0) wsum[w] = v;
    __syncthreads();

    if (t == 0) {
        float s = 0.0f;
        #pragma unroll
        for (int i = 0; i < WPB; ++i) s += wsum[i];
        partials[blockIdx.x] = s;   // plain store, no init required
    }
}

__global__ __launch_bounds__(512)
void l1_order_reduce_kernel(const float* __restrict__ partials,
                            float* __restrict__ out) {
    __shared__ float ssum[8];
    const int t = threadIdx.x;
    const int lane = t & 63;
    const int w = t >> 6;

    float v = partials[t];   // 512 partials, one per block

    #pragma unroll
    for (int off = 32; off > 0; off >>= 1)
        v += __shfl_down(v, off);

    if (lane == 0) ssum[w] = v;
    __syncthreads();

    if (t == 0) {
        float s = 0.0f;
        #pragma unroll
        for (int i = 0; i < 8; ++i) s += ssum[i];
        // scale = 0.5 / (8192 * 128 * 64) = 2^-27 (exact)
        out[0] = s * 7.450580596923828e-09f;   // plain store, no memset needed
    }
}

extern "C" void kernel_launch(void* const* d_in, const int* in_sizes, int n_in,
                              void* d_out, int out_size, void* d_ws, size_t ws_size,
                              hipStream_t stream) {
    const float* pred   = (const float*)d_in[0];
    const float* target = (const float*)d_in[1];
    float* out = (float*)d_out;
    float* partials = (float*)d_ws;

    const int n_rows = in_sizes[0] / ROW_FLOATS;   // 8192
    const int grid   = n_rows / WPB;               // 512

    l1_order_partial_kernel<<<grid, BLOCK, 0, stream>>>(pred, target, partials);
    l1_order_reduce_kernel<<<1, 512, 0, stream>>>(partials, out);
}